// Round 1
// baseline (1537.405 us; speedup 1.0000x reference)
//
#include <hip/hip_runtime.h>
#include <stdint.h>

// ---------------------------------------------------------------------------
// SynthesizedAttention: out[b,q,j] = (softmax(B[b,h,q,:]) @ v)[perm] @ W^T + b
// Shapes: B[4,16,2048,2048] f32, v[4,16,2048,64] f32, W[1024,1024] f32, b[1024]
// K1 : Wp[j][h*64+d] = bf16(W[j][d*16+h])                     (2 MB ws)
// K1b: Vt[bh][d][k]  = bf16(V[bh][k][d])  (pre-transposed V)  (16.8 MB ws)
// K2 : barrier-free streaming exp+P@V: each lane builds its MFMA A-fragment
//      (row = lane&15, k = quad*8 + ks*32) in registers from exp(B); B-frags
//      read directly from L1/L2-resident Vt. No LDS, no __syncthreads.
// K3 : 128x128 bf16 MFMA GEMM: out = attn @ Wp^T + bias (unchanged)
// ---------------------------------------------------------------------------

typedef __attribute__((ext_vector_type(8))) short short8;   // 8 x bf16 bits
typedef __attribute__((ext_vector_type(4))) float float4v;  // mfma accumulator

#define SEQL 2048
#define DH   64
#define NH   16
#define DM   1024

static __device__ inline unsigned short f2bf(float x) {
    unsigned u = __float_as_uint(x);
    unsigned r = (u + 0x7FFFu + ((u >> 16) & 1u)) >> 16;  // round-nearest-even
    return (unsigned short)r;
}

// --------------------------- K1: permute W -> bf16 --------------------------
__global__ __launch_bounds__(256) void wperm_kernel(const float* __restrict__ W,
                                                    unsigned short* __restrict__ Wp) {
    int tid = blockIdx.x * 256 + threadIdx.x;      // 1024*1024 total
    int j   = tid >> 10;
    int rem = tid & 1023;                          // rem = h*64 + d
    int h   = rem >> 6;
    int d   = rem & 63;
    Wp[tid] = f2bf(W[j * 1024 + d * 16 + h]);
}

// ---------------- K1b: V[bh][k][d] f32 -> Vt[bh][d][k] bf16 -----------------
// grid (32 ktiles, 64 bh), block 256. LDS 64x64 tile transpose.
__global__ __launch_bounds__(256) void vtperm_kernel(const float* __restrict__ V,
                                                     unsigned short* __restrict__ Vt) {
    __shared__ __align__(16) unsigned short T[64 * 72];
    const int t  = threadIdx.x;
    const int bh = blockIdx.y;
    const int k0 = blockIdx.x * 64;
    {
        const int kl = t >> 2;                     // local k row 0..63
        const int d0 = (t & 3) * 16;               // d offset 0/16/32/48
        const float* src = V + ((long long)(bh * SEQL + k0 + kl)) * DH + d0;
        float x[16];
        *(float4*)&x[0]  = ((const float4*)src)[0];
        *(float4*)&x[4]  = ((const float4*)src)[1];
        *(float4*)&x[8]  = ((const float4*)src)[2];
        *(float4*)&x[12] = ((const float4*)src)[3];
#pragma unroll
        for (int j = 0; j < 16; j++) T[(d0 + j) * 72 + kl] = f2bf(x[j]);
    }
    __syncthreads();
    {
        const int dd = t >> 2;                     // d row 0..63
        const int ks = (t & 3) * 16;               // k offset 0/16/32/48
        unsigned short* dst = Vt + ((long long)(bh * DH + dd)) * SEQL + k0 + ks;
        *(uint4*)dst       = *(uint4*)&T[dd * 72 + ks];
        *(uint4*)(dst + 8) = *(uint4*)&T[dd * 72 + ks + 8];
    }
}

// ----------------- K2: streaming softmax (unnormalized) + P@V ---------------
// grid (32 qtiles, 64 bh), block 256 (4 independent waves, 16 q-rows each).
// No LDS, no barriers: lane (c,quad) owns A-row c, k-slots quad*8 (+ks*32).
__global__ __launch_bounds__(256, 2) void attn_kernel(const float* __restrict__ B,
                                                      const unsigned short* __restrict__ Vt,
                                                      unsigned short* __restrict__ attn_out) {
    const int t    = threadIdx.x;
    const int lane = t & 63;
    const int wv   = t >> 6;           // wave 0..3 -> q rows wv*16..+15
    const int c    = lane & 15;
    const int quad = lane >> 4;
    const int qt   = blockIdx.x;       // 0..31
    const int bh   = blockIdx.y;       // 0..63
    const int q0   = qt * 64 + wv * 16;

    // this lane's B row (A-fragment row) and Vt base (B-fragment col c)
    const float* Brow = B + ((long long)(bh * SEQL + q0 + c)) * SEQL + quad * 8;
    const unsigned short* Vb = Vt + ((long long)(bh * DH + c)) * SEQL + quad * 8;

    float4v acc[4];
#pragma unroll
    for (int i = 0; i < 4; i++) acc[i] = (float4v){0.f, 0.f, 0.f, 0.f};
    float den = 0.f;

    for (int kk = 0; kk < SEQL; kk += 64) {
        // B-fragment source: 16 floats (k = kk + quad*8 + {0..7} and +32)
        float x[16];
        *(float4*)&x[0]  = *(const float4*)(Brow + kk);
        *(float4*)&x[4]  = *(const float4*)(Brow + kk + 4);
        *(float4*)&x[8]  = *(const float4*)(Brow + kk + 32);
        *(float4*)&x[12] = *(const float4*)(Brow + kk + 36);

        // V fragments direct from global (L1/L2-resident, shared across waves)
        short8 bfr0[4], bfr1[4];
#pragma unroll
        for (int nb = 0; nb < 4; nb++) {
            bfr0[nb] = *(const short8*)(Vb + nb * 16 * SEQL + kk);
            bfr1[nb] = *(const short8*)(Vb + nb * 16 * SEQL + kk + 32);
        }

        // exp + row-sum (per-lane partial; reduced once at the end)
        float s = 0.f;
#pragma unroll
        for (int j = 0; j < 16; j++) { x[j] = __expf(x[j]); s += x[j]; }
        den += s;

        // pack to bf16 A-fragments: 8x v_cvt_pk_bf16_f32 (RNE)
        union { unsigned int u[8]; short8 v[2]; } A;
#pragma unroll
        for (int j = 0; j < 8; j++) {
            unsigned int r;
            asm("v_cvt_pk_bf16_f32 %0, %1, %2" : "=v"(r) : "v"(x[2 * j]), "v"(x[2 * j + 1]));
            A.u[j] = r;
        }

#pragma unroll
        for (int nb = 0; nb < 4; nb++) {
            acc[nb] = __builtin_amdgcn_mfma_f32_16x16x32_bf16(A.v[0], bfr0[nb], acc[nb], 0, 0, 0);
            acc[nb] = __builtin_amdgcn_mfma_f32_16x16x32_bf16(A.v[1], bfr1[nb], acc[nb], 0, 0, 0);
        }
    }

    // full row sums: combine the 4 quad-partials (lanes sharing c)
    den += __shfl_xor(den, 16);
    den += __shfl_xor(den, 32);

    // epilogue: C layout row = quad*4+rr, col = nb*16+c; den for row r sits in lane r
    unsigned short* dst0 = attn_out + ((long long)(bh * SEQL + q0)) * DH;
#pragma unroll
    for (int rr = 0; rr < 4; rr++) {
        const int ql = quad * 4 + rr;
        const float inv = 1.0f / __shfl(den, ql);
#pragma unroll
        for (int nb = 0; nb < 4; nb++) {
            dst0[ql * DH + nb * 16 + c] = f2bf(acc[nb][rr] * inv);
        }
    }
}

// ------------------- K3: out = attn @ Wp^T + bias (fp32) --------------------
// X = attn bf16 [b,h,q,d] read as [r=(b,q)][k=(h,d)]; Wp bf16 [j][k].
// grid: (64 row-tiles, 8 col-tiles), block 256 (2x2 waves of 64x64).
__global__ __launch_bounds__(256) void gemm_kernel(const unsigned short* __restrict__ X,
                                                   const unsigned short* __restrict__ Wp,
                                                   const float* __restrict__ bias,
                                                   float* __restrict__ out) {
    __shared__ __align__(16) unsigned short As[128 * 72];
    __shared__ __align__(16) unsigned short Bs[128 * 72];

    const int t    = threadIdx.x;
    const int lane = t & 63;
    const int wv   = t >> 6;
    const int wm   = wv & 1;
    const int wn   = wv >> 1;
    const int c    = lane & 15;
    const int quad = lane >> 4;

    const int rbase = blockIdx.x * 128;          // global row tile
    const int cbase = blockIdx.y * 128;          // global col tile
    const int b     = rbase >> 11;
    const int q0    = rbase & 2047;

    const int srow = t >> 1;                     // 0..127
    const int sseg = (t & 1) * 32;               // 0 or 32 elems

    float4v acc[4][4];
#pragma unroll
    for (int i = 0; i < 4; i++)
#pragma unroll
        for (int j = 0; j < 4; j++) acc[i][j] = (float4v){0.f, 0.f, 0.f, 0.f};

    for (int kt = 0; kt < 16; ++kt) {            // K-tile = 64 = one head h=kt
        const unsigned short* asrc = X + (((b * 16 + kt) * 2048 + q0 + srow) * 64 + sseg);
        const unsigned short* bsrc = Wp + ((cbase + srow) * 1024 + kt * 64 + sseg);
        uint4 a0 = ((const uint4*)asrc)[0];
        uint4 a1 = ((const uint4*)asrc)[1];
        uint4 a2 = ((const uint4*)asrc)[2];
        uint4 a3 = ((const uint4*)asrc)[3];
        uint4 b0 = ((const uint4*)bsrc)[0];
        uint4 b1 = ((const uint4*)bsrc)[1];
        uint4 b2 = ((const uint4*)bsrc)[2];
        uint4 b3 = ((const uint4*)bsrc)[3];
        *(uint4*)&As[srow * 72 + sseg]      = a0;
        *(uint4*)&As[srow * 72 + sseg + 8]  = a1;
        *(uint4*)&As[srow * 72 + sseg + 16] = a2;
        *(uint4*)&As[srow * 72 + sseg + 24] = a3;
        *(uint4*)&Bs[srow * 72 + sseg]      = b0;
        *(uint4*)&Bs[srow * 72 + sseg + 8]  = b1;
        *(uint4*)&Bs[srow * 72 + sseg + 16] = b2;
        *(uint4*)&Bs[srow * 72 + sseg + 24] = b3;
        __syncthreads();
#pragma unroll
        for (int ks = 0; ks < 2; ks++) {
            short8 af[4], bfr[4];
#pragma unroll
            for (int i = 0; i < 4; i++)
                af[i] = *(const short8*)&As[(wm * 64 + i * 16 + c) * 72 + ks * 32 + quad * 8];
#pragma unroll
            for (int j = 0; j < 4; j++)
                bfr[j] = *(const short8*)&Bs[(wn * 64 + j * 16 + c) * 72 + ks * 32 + quad * 8];
#pragma unroll
            for (int i = 0; i < 4; i++)
#pragma unroll
                for (int j = 0; j < 4; j++)
                    acc[i][j] = __builtin_amdgcn_mfma_f32_16x16x32_bf16(af[i], bfr[j], acc[i][j], 0, 0, 0);
        }
        __syncthreads();
    }

    // epilogue: + bias, fp32 store
#pragma unroll
    for (int i = 0; i < 4; i++) {
#pragma unroll
        for (int rr = 0; rr < 4; rr++) {
            int row = rbase + wm * 64 + i * 16 + quad * 4 + rr;
            float* orow = out + (long long)row * 1024 + cbase + wn * 64;
            const float* brow = bias + cbase + wn * 64;
#pragma unroll
            for (int j = 0; j < 4; j++) {
                int col = j * 16 + c;
                orow[col] = acc[i][j][rr] + brow[col];
            }
        }
    }
}

extern "C" void kernel_launch(void* const* d_in, const int* in_sizes, int n_in,
                              void* d_out, int out_size, void* d_ws, size_t ws_size,
                              hipStream_t stream) {
    const float* B    = (const float*)d_in[0];   // [4,16,2048,2048]
    const float* V    = (const float*)d_in[1];   // [4,16,2048,64]
    const float* W    = (const float*)d_in[2];   // [1024,1024]
    const float* bias = (const float*)d_in[3];   // [1024]
    float* out        = (float*)d_out;           // [4,2048,1024] f32

    unsigned short* attn = (unsigned short*)d_ws;            // 16.8 MB bf16 [b,h,q,d]
    unsigned short* Wp   = attn + 4 * NH * SEQL * DH;        // 2 MB bf16 [j][h*64+d]
    unsigned short* Vt   = Wp + DM * DM;                     // 16.8 MB bf16 [bh][d][k]

    wperm_kernel<<<dim3(4096), dim3(256), 0, stream>>>(W, Wp);
    vtperm_kernel<<<dim3(32, 64), dim3(256), 0, stream>>>(V, Vt);
    attn_kernel<<<dim3(32, 64), dim3(256), 0, stream>>>(B, Vt, attn);
    gemm_kernel<<<dim3(64, 8), dim3(256), 0, stream>>>(attn, Wp, bias, out);
}